// Round 6
// baseline (168.724 us; speedup 1.0000x reference)
//
#include <hip/hip_runtime.h>

#define VOCAB 100000
#define EMBED 128
#define MAX_PATH 20
#define BATCH 32768
#define WPB 4                    // waves per block (block = 256 threads)
#define NBLOCKS (BATCH / WPB)    // 8192

// R6: async gather staging via global_load_lds.
// R5 post-mortem: the compiler sinks register-destined gathers to cut VGPR
// pressure (VGPR=32 despite __launch_bounds__ budget=128), so only ~2-3 of
// the 10 gathers were ever in flight -> latency-bound (VALU 27%, HBM 37%).
// global_load_lds loads consume NO VGPRs and are vmcnt-tracked, so all 10
// per-wave gather instructions stay in flight; one memory round-trip instead
// of five.
//
// Layout (m104/m108 rule: LDS dest = wave-uniform base + lane*16):
//   staging instr (j, h): lane l=(g*16+gl) sources
//       inner_vec[p_g[j]*128 + h*64 + gl*4 ...+4)   (per-lane VGPR address)
//   and HW writes LDS[myl + j*2048 + h*1024 + l*16] -> 1024 contiguous bytes.
//   Readback: lane l ds_read_b128 at the same byte -> fully contiguous wave
//   access = baseline speed, no bank conflicts.
// LDS: 10 KB/wave, 40 KB/block -> 4 blocks/CU (16 waves/CU), 160 gathers
// in flight per CU.
// mask == |code| (codes +/-1 valid, 0 pad; padded path ids are 0 -> row 0
// L1-hot). No device-scope fences (R3: 8x regression). Straight-line code.
__global__ __launch_bounds__(256, 4) void hs_loss_kernel(
    const int* __restrict__ center, const int* __restrict__ target,
    const float* __restrict__ in_emb, const float* __restrict__ inner_vec,
    const int* __restrict__ paths, const float* __restrict__ codes,
    float* __restrict__ partials)
{
    __shared__ float4 lds_buf[WPB * 640];   // 640 float4 = 10240 B per wave

    const int wave = threadIdx.x >> 6;
    const int lane = threadIdx.x & 63;
    const int g    = lane >> 4;   // group 0..3
    const int gl   = lane & 15;   // lane within group
    const int b = blockIdx.x * WPB + wave;

    const int c = center[b];
    const int t = target[b];

    // h fragment in registers (reused 5x): floats [4gl..+4) and [64+4gl..+4)
    const float4* hp = (const float4*)(in_emb + (size_t)c * EMBED);
    const float4 h0 = hp[gl];
    const float4 h1 = hp[gl + 16];

    // Group g's 5 (path, code) pairs: nodes g, g+4, ..., g+16
    const int base = t * MAX_PATH + g;
    int   p[5];
    float cd[5];
    #pragma unroll
    for (int j = 0; j < 5; ++j) {
        p[j]  = paths[base + 4 * j];
        cd[j] = codes[base + 4 * j];
    }

    // Stage all 20 rows (10 x 1024B async instructions, all in flight).
    float4* myl = lds_buf + wave * 640;
    #pragma unroll
    for (int j = 0; j < 5; ++j) {
        const float* src = inner_vec + (size_t)p[j] * EMBED + 4 * gl;
        __builtin_amdgcn_global_load_lds(
            (const __attribute__((address_space(1))) unsigned int*)(src),
            (__attribute__((address_space(3))) unsigned int*)(myl + j * 128),
            16, 0, 0);
        __builtin_amdgcn_global_load_lds(
            (const __attribute__((address_space(1))) unsigned int*)(src + 64),
            (__attribute__((address_space(3))) unsigned int*)(myl + j * 128 + 64),
            16, 0, 0);
    }
    __syncthreads();   // drains vmcnt (incl. global_load_lds) + orders LDS

    // Math: contiguous ds_read_b128 per (j,half), same fragment math as R5.
    float acc = 0.f;
    #pragma unroll
    for (int j = 0; j < 5; ++j) {
        const float4 a0 = myl[j * 128 + lane];
        const float4 a1 = myl[j * 128 + 64 + lane];
        float d = h0.x * a0.x;
        d = fmaf(h0.y, a0.y, d);
        d = fmaf(h0.z, a0.z, d);
        d = fmaf(h0.w, a0.w, d);
        float e = h1.x * a1.x;
        e = fmaf(h1.y, a1.y, e);
        e = fmaf(h1.z, a1.z, e);
        e = fmaf(h1.w, a1.w, e);
        d += e;
        d += __shfl_xor(d, 1, 64);
        d += __shfl_xor(d, 2, 64);
        d += __shfl_xor(d, 4, 64);
        d += __shfl_xor(d, 8, 64);
        const float x  = cd[j] * d;
        const float ls = fminf(x, 0.f) - __logf(1.f + __expf(-fabsf(x)));
        acc = fmaf(fabsf(cd[j]), ls, acc);   // |code| == mask (0 on padding)
    }

    // sum across the 4 groups
    acc += __shfl_xor(acc, 16, 64);
    acc += __shfl_xor(acc, 32, 64);

    __shared__ float ws[WPB];
    if (lane == 0) ws[wave] = -acc;
    __syncthreads();
    if (threadIdx.x == 0) {
        partials[blockIdx.x] = ws[0] + ws[1] + ws[2] + ws[3];
    }
}

__global__ __launch_bounds__(256) void hs_reduce_kernel(
    const float* __restrict__ partials, float* __restrict__ out)
{
    const float4* p4 = (const float4*)partials;
    float s = 0.f;
    #pragma unroll
    for (int i = 0; i < NBLOCKS / 4 / 256; ++i) {
        const float4 v = p4[i * 256 + threadIdx.x];
        s += (v.x + v.y) + (v.z + v.w);
    }
    #pragma unroll
    for (int off = 32; off; off >>= 1) s += __shfl_xor(s, off, 64);
    __shared__ float ws[4];
    const int wave = threadIdx.x >> 6;
    const int lane = threadIdx.x & 63;
    if (lane == 0) ws[wave] = s;
    __syncthreads();
    if (threadIdx.x == 0) {
        out[0] = (ws[0] + ws[1] + ws[2] + ws[3]) / (float)BATCH;
    }
}

extern "C" void kernel_launch(void* const* d_in, const int* in_sizes, int n_in,
                              void* d_out, int out_size, void* d_ws, size_t ws_size,
                              hipStream_t stream) {
    const int*   center    = (const int*)d_in[0];
    const int*   target    = (const int*)d_in[1];
    const float* in_emb    = (const float*)d_in[2];
    const float* inner_vec = (const float*)d_in[3];
    const int*   paths     = (const int*)d_in[4];
    const float* codes     = (const float*)d_in[5];
    // d_in[6] (masks) intentionally unused: mask == |code|
    float* out = (float*)d_out;
    float* partials = (float*)d_ws;   // 8192 floats = 32 KB scratch

    hs_loss_kernel<<<NBLOCKS, 256, 0, stream>>>(
        center, target, in_emb, inner_vec, paths, codes, partials);
    hs_reduce_kernel<<<1, 256, 0, stream>>>(partials, out);
}